// Round 8
// baseline (181.153 us; speedup 1.0000x reference)
//
#include <hip/hip_runtime.h>

#define T_LEN 120000
#define LBLK 32           // samples per scan block (divides 40000)
#define PBLK 3750         // number of scan blocks
#define SEG_LEN 25        // blocks per scan segment
#define NSEG 150          // segments (SEG_LEN*NSEG == PBLK)
#define BATCH 4
#define K0 1250           // first valid block (t = 40000)
#define NKV 1250          // valid blocks (t in [40000, 80000))
#define IB_LO 1250        // ibuf holds block states m in [1250, 2500]
#define IB_HI 2500
#define DENOM 20480000.0  // 2 * 4 * 64 * 40000 (each |diff| counted twice)
#define YSTR 130          // halves per ys row: 128 ch + 2 pad (odd dword stride)
#define NSLOT 128         // atomic accumulation slots

typedef _Float16 half8 __attribute__((ext_vector_type(8)));
typedef float f32x4 __attribute__((ext_vector_type(4)));

__device__ __forceinline__ float fast_tanh(float x) {
  float e = __expf(2.0f * x);
  return 1.0f - 2.0f / (e + 1.0f);
}

// Harness may store the reference's float64 arrays as f64 or f32. Detect via
// a2[0] = r^2 in (0.9,1.0) (f32-reinterpret fails the window). Data-stable.
__device__ __forceinline__ bool coeffs_are_f64(const void* a2p) {
  double probe = *(const double*)a2p;
  return probe > 0.9 && probe < 1.0;
}
__device__ __forceinline__ double coeff_d(const void* p, bool f64, int ch) {
  return f64 ? ((const double*)p)[ch] : (double)((const float*)p)[ch];
}

// A^e for A = [[-a1,-a2],[1,0]] by repeated squaring (f64)
__device__ __forceinline__ void mat_pow(double A1, double A2, int e,
                                        double& r00, double& r01,
                                        double& r10, double& r11) {
  double m00 = -A1, m01 = -A2, m10 = 1.0, m11 = 0.0;
  r00 = 1.0; r01 = 0.0; r10 = 0.0; r11 = 1.0;
  while (e) {
    if (e & 1) {
      double t00 = r00 * m00 + r01 * m10, t01 = r00 * m01 + r01 * m11;
      double t10 = r10 * m00 + r11 * m10, t11 = r10 * m01 + r11 * m11;
      r00 = t00; r01 = t01; r10 = t10; r11 = t11;
    }
    e >>= 1;
    if (e) {
      double t00 = m00 * m00 + m01 * m10, t01 = m00 * m01 + m01 * m11;
      double t10 = m10 * m00 + m11 * m10, t11 = m10 * m01 + m11 * m11;
      m00 = t00; m01 = t01; m10 = t10; m11 = t11;
    }
  }
}

// Pass 1: per (row, block) forced response with zero init, f32, 32 steps.
// 5 waves/wg, wave w -> block k = 5*bx + w. x via wave-uniform scalar loads.
// rows r = i*8 + d*4 + b. Block (0,0) also zeroes the wsum slots.
__global__ __launch_bounds__(320) void pass1(
    const float* __restrict__ pred, const float* __restrict__ tgt,
    const void* a1p, const void* a2p, const void* b0p,
    double* __restrict__ fbuf, double* __restrict__ wsum)
{
  int tid = threadIdx.x;
  int r = blockIdx.y;
  if (blockIdx.x == 0 && r == 0 && tid < NSLOT) wsum[tid] = 0.0;
  int w = __builtin_amdgcn_readfirstlane(tid >> 6);
  int ch = tid & 63;
  int i = r >> 3, d = (r >> 2) & 1, b = r & 3;
  int k = blockIdx.x * 5 + w;
  const float* sig = (i ? tgt : pred) + b * T_LEN;
  int base = k * LBLK;
  const float* xp = sig + (d ? (T_LEN - LBLK - base) : base);  // uniform

  bool f64c = coeffs_are_f64(a2p);
  float A1 = (float)coeff_d(a1p, f64c, ch);
  float A2 = (float)coeff_d(a2p, f64c, ch);
  float B0 = (float)coeff_d(b0p, f64c, ch);
  float y1 = 0.0f, y2 = 0.0f;
  if (d == 0) {
    #pragma unroll
    for (int j = 0; j < LBLK; ++j) {
      float y = fmaf(-A1, y1, fmaf(-A2, y2, B0 * xp[j]));
      y2 = y1; y1 = y;
    }
  } else {
    #pragma unroll
    for (int j = 0; j < LBLK; ++j) {
      float y = fmaf(-A1, y1, fmaf(-A2, y2, B0 * xp[LBLK - 1 - j]));
      y2 = y1; y1 = y;
    }
  }
  ((double2*)fbuf)[(size_t)k * 1024 + r * 64 + ch] =
      make_double2((double)y1, (double)y2);
}

// Pass 2a: per-segment aggregate (forced response of 25 blocks, zero init), f64.
__global__ __launch_bounds__(64) void pass2a(
    const void* a1p, const void* a2p,
    const double* __restrict__ fbuf, double* __restrict__ sbuf)
{
  int seg = blockIdx.x >> 4;
  int s = ((blockIdx.x & 15) << 6) + threadIdx.x;
  int ch = s & 63;
  bool f64 = coeffs_are_f64(a2p);
  double r00, r01, r10, r11;
  mat_pow(coeff_d(a1p, f64, ch), coeff_d(a2p, f64, ch), LBLK, r00, r01, r10, r11);
  const double2* fb = (const double2*)fbuf;
  double y1 = 0.0, y2 = 0.0;
  #pragma unroll 1
  for (int jj = 0; jj < SEG_LEN / 5; ++jj) {
    size_t kb = (size_t)(seg * SEG_LEN + jj * 5) * 1024 + s;
    double2 f0 = fb[kb], f1 = fb[kb + 1024], f2 = fb[kb + 2048],
            f3 = fb[kb + 3072], f4 = fb[kb + 4096];
    double n1, n2;
    n1 = r00*y1 + r01*y2 + f0.x; n2 = r10*y1 + r11*y2 + f0.y; y1=n1; y2=n2;
    n1 = r00*y1 + r01*y2 + f1.x; n2 = r10*y1 + r11*y2 + f1.y; y1=n1; y2=n2;
    n1 = r00*y1 + r01*y2 + f2.x; n2 = r10*y1 + r11*y2 + f2.y; y1=n1; y2=n2;
    n1 = r00*y1 + r01*y2 + f3.x; n2 = r10*y1 + r11*y2 + f3.y; y1=n1; y2=n2;
    n1 = r00*y1 + r01*y2 + f4.x; n2 = r10*y1 + r11*y2 + f4.y; y1=n1; y2=n2;
  }
  ((double2*)sbuf)[(size_t)seg * 1024 + s] = make_double2(y1, y2);
}

// Pass 2b: serial scan over 150 segment aggregates -> segment-start states.
__global__ __launch_bounds__(256) void pass2b(
    const void* a1p, const void* a2p,
    const double* __restrict__ sbuf, double* __restrict__ tbuf)
{
  int s = blockIdx.x * 256 + threadIdx.x;
  int ch = s & 63;
  bool f64 = coeffs_are_f64(a2p);
  double r00, r01, r10, r11;
  mat_pow(coeff_d(a1p, f64, ch), coeff_d(a2p, f64, ch), LBLK * SEG_LEN,
          r00, r01, r10, r11);
  const double2* sb = (const double2*)sbuf;
  double2* tb = (double2*)tbuf;
  double y1 = 0.0, y2 = 0.0;
  #pragma unroll 1
  for (int bb = 0; bb < NSEG; bb += 15) {
    double2 f[15];
    #pragma unroll
    for (int q = 0; q < 15; ++q) f[q] = sb[(size_t)(bb + q) * 1024 + s];
    #pragma unroll
    for (int q = 0; q < 15; ++q) {
      tb[(size_t)(bb + q) * 1024 + s] = make_double2(y1, y2);
      double n1 = r00 * y1 + r01 * y2 + f[q].x;
      double n2 = r10 * y1 + r11 * y2 + f[q].y;
      y1 = n1; y2 = n2;
    }
  }
}

// Pass 2c: expand segments 50..100 into per-block states m in [1250, 2500].
__global__ __launch_bounds__(64) void pass2c(
    const void* a1p, const void* a2p,
    const double* __restrict__ fbuf, const double* __restrict__ tbuf,
    double* __restrict__ ibuf)
{
  int seg = 50 + (blockIdx.x >> 4);
  int s = ((blockIdx.x & 15) << 6) + threadIdx.x;
  int ch = s & 63;
  bool f64 = coeffs_are_f64(a2p);
  double r00, r01, r10, r11;
  mat_pow(coeff_d(a1p, f64, ch), coeff_d(a2p, f64, ch), LBLK, r00, r01, r10, r11);
  const double2* fb = (const double2*)fbuf;
  double2* ib = (double2*)ibuf;
  double2 v = ((const double2*)tbuf)[(size_t)seg * 1024 + s];
  double y1 = v.x, y2 = v.y;
  #pragma unroll 1
  for (int jj = 0; jj < SEG_LEN / 5; ++jj) {
    double2 f[5];
    #pragma unroll
    for (int q = 0; q < 5; ++q)
      f[q] = fb[(size_t)(seg * SEG_LEN + jj * 5 + q) * 1024 + s];
    #pragma unroll
    for (int q = 0; q < 5; ++q) {
      int m = seg * SEG_LEN + jj * 5 + q;
      if (m <= IB_HI)
        ib[(size_t)(m - IB_LO) * 1024 + s] = make_double2(y1, y2);
      double n1 = r00 * y1 + r01 * y2 + f[q].x;
      double n2 = r10 * y1 + r11 * y2 + f[q].y;
      y1 = n1; y2 = n2;
    }
  }
}

// Pass 3: wg = (2 consecutive k-blocks, b). Each wave runs TWO independent
// 32-step f32 chains (ILP) from exact f64 ibuf states, writes two f16 tiles,
// one barrier, then MFMA 16x16x32_f16 on both tiles + tanh + |p-t| reduce.
__global__ __launch_bounds__(256, 4) void pass3(
    const float* __restrict__ pred, const float* __restrict__ tgt,
    const void* a1p, const void* a2p, const void* b0p,
    const float* __restrict__ W, const double* __restrict__ ibuf,
    double* __restrict__ wsum)
{
  int k0 = K0 + blockIdx.x * 2;
  int b = blockIdx.y;
  int tid = threadIdx.x;
  __shared__ __align__(16) _Float16 ys[2][64 * YSTR];
  __shared__ float red[4];

  int g = tid >> 6, lane = tid & 63;
  int gu = __builtin_amdgcn_readfirstlane(g);
  int iu = gu >> 1, du = gu & 1;
  int ch = lane;
  int n0 = gu * 16;
  int lm = lane & 15, quad = lane >> 4;

  bool f64 = coeffs_are_f64(a2p);
  double A1d = coeff_d(a1p, f64, ch), A2d = coeff_d(a2p, f64, ch);
  double B0d = coeff_d(b0p, f64, ch);
  float A1 = (float)A1d, A2 = (float)A2d, B0 = (float)B0d;
  float IA2 = (float)(1.0 / A2d);

  // W fragments f32 -> f16 in registers (64 VGPR), reused for both tiles
  half8 wf[4][4];
  #pragma unroll
  for (int m0 = 0; m0 < 4; ++m0) {
    #pragma unroll
    for (int q = 0; q < 4; ++q) {
      const float* wp = W + (m0 * 16 + lm) * 128 + q * 32 + quad * 8;
      float4 wa = *(const float4*)wp, wb = *(const float4*)(wp + 4);
      half8 h;
      h[0] = (_Float16)wa.x; h[1] = (_Float16)wa.y;
      h[2] = (_Float16)wa.z; h[3] = (_Float16)wa.w;
      h[4] = (_Float16)wb.x; h[5] = (_Float16)wb.y;
      h[6] = (_Float16)wb.z; h[7] = (_Float16)wb.w;
      wf[m0][q] = h;
    }
  }

  const float* xp = (iu ? tgt : pred) + b * T_LEN + k0 * LBLK; // uniform
  int s = (iu * 8 + du * 4 + b) * 64 + ch;
  const double2* ib = (const double2*)ibuf;
  double2 va, vb;
  if (du == 0) {
    va = ib[(size_t)(k0 - IB_LO) * 1024 + s];
    vb = ib[(size_t)(k0 + 1 - IB_LO) * 1024 + s];
  } else {
    va = ib[(size_t)(PBLK - k0 - IB_LO) * 1024 + s];
    vb = ib[(size_t)(PBLK - k0 - 1 - IB_LO) * 1024 + s];
  }
  float sa0 = (float)va.x, sa1 = (float)va.y;
  float sb0 = (float)vb.x, sb1 = (float)vb.y;

  // ---- two interleaved 32-step chains (A: block k0, B: block k0+1) ----
  if (du == 0) {
    #pragma unroll
    for (int tt = 0; tt < LBLK; ++tt) {
      float xa = xp[tt], xb = xp[LBLK + tt];
      float ya = fmaf(-A1, sa0, fmaf(-A2, sa1, B0 * xa));
      float yb = fmaf(-A1, sb0, fmaf(-A2, sb1, B0 * xb));
      ys[0][(2 * tt + iu) * YSTR + ch] = (_Float16)ya;
      ys[1][(2 * tt + iu) * YSTR + ch] = (_Float16)yb;
      sa1 = sa0; sa0 = ya; sb1 = sb0; sb0 = yb;
    }
  } else {
    #pragma unroll
    for (int tt = 0; tt < LBLK; ++tt) {
      float xa = xp[tt], xb = xp[LBLK + tt];
      ys[0][(2 * tt + iu) * YSTR + 64 + ch] = (_Float16)sa0;
      ys[1][(2 * tt + iu) * YSTR + 64 + ch] = (_Float16)sb0;
      float ra = (fmaf(-A1, sa1, B0 * xa) - sa0) * IA2;
      float rb = (fmaf(-A1, sb1, B0 * xb) - sb0) * IA2;
      sa0 = sa1; sa1 = ra; sb0 = sb1; sb1 = rb;
    }
  }
  __syncthreads();

  // ---- MFMA + epilogue on both tiles ----
  float loss = 0.0f;
  #pragma unroll
  for (int kk = 0; kk < 2; ++kk) {
    const _Float16* yrow = &ys[kk][(n0 + lm) * YSTR + quad * 8];
    half8 bf0 = *(const half8*)(yrow);
    half8 bf1 = *(const half8*)(yrow + 32);
    half8 bf2 = *(const half8*)(yrow + 64);
    half8 bf3 = *(const half8*)(yrow + 96);
    #pragma unroll
    for (int m0 = 0; m0 < 4; ++m0) {
      f32x4 c = {0.f, 0.f, 0.f, 0.f};
      c = __builtin_amdgcn_mfma_f32_16x16x32_f16(wf[m0][0], bf0, c, 0, 0, 0);
      c = __builtin_amdgcn_mfma_f32_16x16x32_f16(wf[m0][1], bf1, c, 0, 0, 0);
      c = __builtin_amdgcn_mfma_f32_16x16x32_f16(wf[m0][2], bf2, c, 0, 0, 0);
      c = __builtin_amdgcn_mfma_f32_16x16x32_f16(wf[m0][3], bf3, c, 0, 0, 0);
      #pragma unroll
      for (int r = 0; r < 4; ++r) {
        float vv = fast_tanh(c[r]);
        float p = __shfl_xor(vv, 1);   // partner col = other input, same t
        loss += fabsf(vv - p);
      }
    }
  }

  // block reduction -> one double atomic per wg, spread over 128 slots
  #pragma unroll
  for (int off = 32; off > 0; off >>= 1) loss += __shfl_down(loss, off);
  if ((tid & 63) == 0) red[tid >> 6] = loss;
  __syncthreads();
  if (tid == 0) {
    int slot = (blockIdx.x * 4 + blockIdx.y) & (NSLOT - 1);
    atomicAdd(&wsum[slot], (double)(red[0] + red[1] + red[2] + red[3]));
  }
}

__global__ __launch_bounds__(128) void finalize(
    const double* __restrict__ wsum, float* __restrict__ out) {
  __shared__ double part[2];
  int tid = threadIdx.x;
  double v = wsum[tid];
  #pragma unroll
  for (int off = 32; off > 0; off >>= 1) v += __shfl_down(v, off);
  if ((tid & 63) == 0) part[tid >> 6] = v;
  __syncthreads();
  if (tid == 0) out[0] = (float)((part[0] + part[1]) / DENOM);
}

extern "C" void kernel_launch(void* const* d_in, const int* in_sizes, int n_in,
                              void* d_out, int out_size, void* d_ws, size_t ws_size,
                              hipStream_t stream) {
  const float* pred = (const float*)d_in[0];
  const float* tgt  = (const float*)d_in[1];
  const void* a1p = d_in[2];
  const void* a2p = d_in[3];
  const void* b0p = d_in[4];
  const float* W  = (const float*)d_in[5];
  float* out = (float*)d_out;

  double* base = (double*)d_ws;
  double* wsum = base;                                   // [128]
  double* fbuf = base + NSLOT;                           // [3750][1024][2]
  double* sbuf = fbuf + (size_t)PBLK * 1024 * 2;         // [150][1024][2]
  double* tbuf = sbuf + (size_t)NSEG * 1024 * 2;         // [150][1024][2]
  double* ibuf = tbuf + (size_t)NSEG * 1024 * 2;         // [1251][1024][2]

  pass1<<<dim3(750, 16), 320, 0, stream>>>(pred, tgt, a1p, a2p, b0p, fbuf, wsum);
  pass2a<<<NSEG * 16, 64, 0, stream>>>(a1p, a2p, fbuf, sbuf);
  pass2b<<<dim3(4), 256, 0, stream>>>(a1p, a2p, sbuf, tbuf);
  pass2c<<<51 * 16, 64, 0, stream>>>(a1p, a2p, fbuf, tbuf, ibuf);
  pass3<<<dim3(NKV / 2, BATCH), 256, 0, stream>>>(pred, tgt, a1p, a2p, b0p,
                                                  W, ibuf, wsum);
  finalize<<<1, 128, 0, stream>>>(wsum, out);
}

// Round 9
// 173.446 us; speedup vs baseline: 1.0444x; 1.0444x over previous
//
#include <hip/hip_runtime.h>

#define T_LEN 120000
#define LBLK 160          // scan block length (divides 40000)
#define PBLK 750          // scan blocks
#define SEG_LEN 25        // blocks per scan segment
#define NSEG 30           // segments
#define BATCH 4
#define JB_LO 625         // jbuf holds 64-sample states m in [625, 1250]
#define JB_HI 1250
#define NJV 625           // valid 64-t blocks (t in [40000, 80000))
#define DENOM 20480000.0  // 2 * 4 * 64 * 40000 (each |diff| counted twice)
#define YSTR 130          // halves per ys row: 128 ch + 2 pad
#define NSLOT 128         // atomic accumulation slots

typedef _Float16 half8 __attribute__((ext_vector_type(8)));
typedef float f32x4 __attribute__((ext_vector_type(4)));

__device__ __forceinline__ float fast_tanh(float x) {
  float e = __expf(2.0f * x);
  return 1.0f - 2.0f / (e + 1.0f);
}

// Harness may store the reference's float64 arrays as f64 or f32. Detect via
// a2[0] = r^2 in (0.9,1.0) (f32-reinterpret fails the window). Data-stable.
__device__ __forceinline__ bool coeffs_are_f64(const void* a2p) {
  double probe = *(const double*)a2p;
  return probe > 0.9 && probe < 1.0;
}
__device__ __forceinline__ double coeff_d(const void* p, bool f64, int ch) {
  return f64 ? ((const double*)p)[ch] : (double)((const float*)p)[ch];
}

// A^e for A = [[-a1,-a2],[1,0]] by repeated squaring (f64)
__device__ __forceinline__ void mat_pow(double A1, double A2, int e,
                                        double& r00, double& r01,
                                        double& r10, double& r11) {
  double m00 = -A1, m01 = -A2, m10 = 1.0, m11 = 0.0;
  r00 = 1.0; r01 = 0.0; r10 = 0.0; r11 = 1.0;
  while (e) {
    if (e & 1) {
      double t00 = r00 * m00 + r01 * m10, t01 = r00 * m01 + r01 * m11;
      double t10 = r10 * m00 + r11 * m10, t11 = r10 * m01 + r11 * m11;
      r00 = t00; r01 = t01; r10 = t10; r11 = t11;
    }
    e >>= 1;
    if (e) {
      double t00 = m00 * m00 + m01 * m10, t01 = m00 * m01 + m01 * m11;
      double t10 = m10 * m00 + m11 * m10, t11 = m10 * m01 + m11 * m11;
      m00 = t00; m01 = t01; m10 = t10; m11 = t11;
    }
  }
}

// Pass 1: per (row, block) forced response with zero initial state, f32.
// rows r = i*8 + d*4 + b  (i: 0=pred 1=target, d: 0=fwd 1=bwd, b: batch)
__global__ __launch_bounds__(64) void pass1(
    const float* __restrict__ pred, const float* __restrict__ tgt,
    const void* a1p, const void* a2p, const void* b0p,
    double* __restrict__ fbuf)
{
  int k = blockIdx.x, r = blockIdx.y;
  int i = r >> 3, d = (r >> 2) & 1, b = r & 3;
  const float* sig = (i ? tgt : pred) + b * T_LEN;
  __shared__ float xs[LBLK];
  int base = k * LBLK;
  for (int j = threadIdx.x; j < LBLK; j += 64)
    xs[j] = d ? sig[T_LEN - 1 - (base + j)] : sig[base + j];
  __syncthreads();
  int ch = threadIdx.x;
  bool f64 = coeffs_are_f64(a2p);
  float A1 = (float)coeff_d(a1p, f64, ch);
  float A2 = (float)coeff_d(a2p, f64, ch);
  float B0 = (float)coeff_d(b0p, f64, ch);
  float y1 = 0.0f, y2 = 0.0f;
  for (int j = 0; j < LBLK; ++j) {
    float y = fmaf(-A1, y1, fmaf(-A2, y2, B0 * xs[j]));
    y2 = y1; y1 = y;
  }
  int s = r * 64 + ch;
  ((double2*)fbuf)[(size_t)k * 1024 + s] = make_double2((double)y1, (double)y2);
}

// Pass 2a: per-segment aggregate (forced response of 25 blocks, zero init), f64.
__global__ __launch_bounds__(64) void pass2a(
    const void* a1p, const void* a2p,
    const double* __restrict__ fbuf, double* __restrict__ sbuf)
{
  int seg = blockIdx.x >> 4;
  int s = ((blockIdx.x & 15) << 6) + threadIdx.x;
  int ch = s & 63;
  bool f64 = coeffs_are_f64(a2p);
  double r00, r01, r10, r11;
  mat_pow(coeff_d(a1p, f64, ch), coeff_d(a2p, f64, ch), LBLK, r00, r01, r10, r11);
  const double2* fb = (const double2*)fbuf;
  double y1 = 0.0, y2 = 0.0;
  #pragma unroll 1
  for (int jj = 0; jj < SEG_LEN / 5; ++jj) {
    size_t kb = (size_t)(seg * SEG_LEN + jj * 5) * 1024 + s;
    double2 f0 = fb[kb], f1 = fb[kb + 1024], f2 = fb[kb + 2048],
            f3 = fb[kb + 3072], f4 = fb[kb + 4096];
    double n1, n2;
    n1 = r00*y1 + r01*y2 + f0.x; n2 = r10*y1 + r11*y2 + f0.y; y1=n1; y2=n2;
    n1 = r00*y1 + r01*y2 + f1.x; n2 = r10*y1 + r11*y2 + f1.y; y1=n1; y2=n2;
    n1 = r00*y1 + r01*y2 + f2.x; n2 = r10*y1 + r11*y2 + f2.y; y1=n1; y2=n2;
    n1 = r00*y1 + r01*y2 + f3.x; n2 = r10*y1 + r11*y2 + f3.y; y1=n1; y2=n2;
    n1 = r00*y1 + r01*y2 + f4.x; n2 = r10*y1 + r11*y2 + f4.y; y1=n1; y2=n2;
  }
  ((double2*)sbuf)[(size_t)seg * 1024 + s] = make_double2(y1, y2);
}

// Pass 2b: serial scan over the 30 segment aggregates -> segment-start states.
__global__ __launch_bounds__(256) void pass2b(
    const void* a1p, const void* a2p,
    const double* __restrict__ sbuf, double* __restrict__ tbuf)
{
  int s = blockIdx.x * 256 + threadIdx.x;
  int ch = s & 63;
  bool f64 = coeffs_are_f64(a2p);
  double r00, r01, r10, r11;
  mat_pow(coeff_d(a1p, f64, ch), coeff_d(a2p, f64, ch), LBLK * SEG_LEN,
          r00, r01, r10, r11);
  const double2* sb = (const double2*)sbuf;
  double2* tb = (double2*)tbuf;
  double y1 = 0.0, y2 = 0.0;
  #pragma unroll 1
  for (int bb = 0; bb < NSEG; bb += 15) {
    double2 f[15];
    #pragma unroll
    for (int q = 0; q < 15; ++q) f[q] = sb[(size_t)(bb + q) * 1024 + s];
    #pragma unroll
    for (int q = 0; q < 15; ++q) {
      tb[(size_t)(bb + q) * 1024 + s] = make_double2(y1, y2);
      double n1 = r00 * y1 + r01 * y2 + f[q].x;
      double n2 = r10 * y1 + r11 * y2 + f[q].y;
      y1 = n1; y2 = n2;
    }
  }
}

// Pass 2c: per (scan block k in [250,500], row r): compose <=24 block
// aggregates from tbuf[seg], then walk 160 exact f64 sample-steps over the
// signal, emitting f32 state snapshots at every 64-sample boundary -> jbuf.
__global__ __launch_bounds__(64) void pass2c(
    const float* __restrict__ pred, const float* __restrict__ tgt,
    const void* a1p, const void* a2p, const void* b0p,
    const double* __restrict__ fbuf, const double* __restrict__ tbuf,
    float2* __restrict__ jbuf)
{
  int k = 250 + blockIdx.x;   // scan block, p0 = 160k in [40000, 80000]
  int r = blockIdx.y;
  int ch = threadIdx.x;
  int i = r >> 3, d = (r >> 2) & 1, b = r & 3;
  int s = r * 64 + ch;
  bool f64 = coeffs_are_f64(a2p);
  double A1 = coeff_d(a1p, f64, ch), A2 = coeff_d(a2p, f64, ch);
  double B0 = coeff_d(b0p, f64, ch);
  double r00, r01, r10, r11;
  mat_pow(A1, A2, LBLK, r00, r01, r10, r11);

  int seg = k / SEG_LEN, j0 = k - seg * SEG_LEN;   // j0 in [0,24]
  double2 v0 = ((const double2*)tbuf)[(size_t)seg * 1024 + s];
  double y1 = v0.x, y2 = v0.y;
  const double2* fb = (const double2*)fbuf + (size_t)(seg * SEG_LEN) * 1024 + s;
  #pragma unroll 1
  for (int bb = 0; bb < 24; bb += 8) {
    double2 f[8];
    #pragma unroll
    for (int q = 0; q < 8; ++q) f[q] = fb[(size_t)(bb + q) * 1024];
    #pragma unroll
    for (int q = 0; q < 8; ++q) {
      if (bb + q < j0) {    // uniform predicate
        double n1 = r00 * y1 + r01 * y2 + f[q].x;
        double n2 = r10 * y1 + r11 * y2 + f[q].y;
        y1 = n1; y2 = n2;
      }
    }
  }

  // exact f64 sample walk over this block, wave-uniform x loads
  const float* sig = (i ? tgt : pred) + b * T_LEN;
  int p0 = k * LBLK;
  #pragma unroll 1
  for (int idx = 0; idx < LBLK; ++idx) {
    int p = p0 + idx;
    if ((p & 63) == 0) {
      int m = p >> 6;
      if (m <= JB_HI)
        jbuf[(size_t)(m - JB_LO) * 1024 + s] = make_float2((float)y1, (float)y2);
    }
    double x = (double)(d ? sig[T_LEN - 1 - p] : sig[p]);
    double y = fma(-A1, y1, fma(-A2, y2, B0 * x));
    y2 = y1; y1 = y;
  }
}

// Pass 3: wg = (64-t block j, batch b), grid 625x4 = 2500 wgs. No f64.
// Each wave (i,d) runs a 64-step f32 chain from its exact jbuf state,
// fills the 128-col f16 tile (col = 2t+i, fwd ch 0-63 / bwd ch 64-127),
// one barrier, then 2x 16-col MFMA slices + tanh + |p-t| reduce.
__global__ __launch_bounds__(256, 4) void pass3(
    const float* __restrict__ pred, const float* __restrict__ tgt,
    const void* a1p, const void* a2p, const void* b0p,
    const float* __restrict__ W, const float2* __restrict__ jbuf,
    double* __restrict__ wsum)
{
  int j = JB_LO + blockIdx.x;     // t in [64j, 64j+64)
  int b = blockIdx.y;
  int tid = threadIdx.x;
  __shared__ __align__(16) _Float16 ys[128 * YSTR];
  __shared__ float red[4];

  int g = tid >> 6, lane = tid & 63;
  int gu = __builtin_amdgcn_readfirstlane(g);
  int iu = gu >> 1, du = gu & 1;
  int ch = lane;
  int lm = lane & 15, quad = lane >> 4;

  bool f64 = coeffs_are_f64(a2p);
  double A2d = coeff_d(a2p, f64, ch);
  float A1 = (float)coeff_d(a1p, f64, ch);
  float A2 = (float)A2d;
  float B0 = (float)coeff_d(b0p, f64, ch);
  float IA2 = (float)(1.0 / A2d);

  // W fragments f32 -> f16 in registers, built once per wg
  half8 wf[4][4];
  #pragma unroll
  for (int m0 = 0; m0 < 4; ++m0) {
    #pragma unroll
    for (int q = 0; q < 4; ++q) {
      const float* wp = W + (m0 * 16 + lm) * 128 + q * 32 + quad * 8;
      float4 wa = *(const float4*)wp, wb = *(const float4*)(wp + 4);
      half8 h;
      h[0] = (_Float16)wa.x; h[1] = (_Float16)wa.y;
      h[2] = (_Float16)wa.z; h[3] = (_Float16)wa.w;
      h[4] = (_Float16)wb.x; h[5] = (_Float16)wb.y;
      h[6] = (_Float16)wb.z; h[7] = (_Float16)wb.w;
      wf[m0][q] = h;
    }
  }

  // exact state for this wave's chain (fwd: jbuf[j]; bwd: jbuf[1875-j])
  int s = (iu * 8 + du * 4 + b) * 64 + ch;
  int jj = du ? (JB_HI - JB_LO - (j - JB_LO)) : (j - JB_LO); // 1250-j or j-625
  float2 v = jbuf[(size_t)jj * 1024 + s];
  float st0 = v.x, st1 = v.y;

  const float* xp = (iu ? tgt : pred) + b * T_LEN + j * 64;  // wave-uniform

  // ---- recurrence: 64 steps, fill tile ----
  if (du == 0) {
    #pragma unroll
    for (int tt = 0; tt < 64; ++tt) {
      float y = fmaf(-A1, st0, fmaf(-A2, st1, B0 * xp[tt]));
      ys[(2 * tt + iu) * YSTR + ch] = (_Float16)y;
      st1 = st0; st0 = y;
    }
  } else {
    #pragma unroll
    for (int tt = 0; tt < 64; ++tt) {
      ys[(2 * tt + iu) * YSTR + 64 + ch] = (_Float16)st0;
      float ym2 = (fmaf(-A1, st1, B0 * xp[tt]) - st0) * IA2;
      st0 = st1; st1 = ym2;
    }
  }
  __syncthreads();

  // ---- MFMA: wave handles 2 slices of 16 cols ----
  float loss = 0.0f;
  #pragma unroll
  for (int sl = 0; sl < 2; ++sl) {
    int n0 = sl * 64 + gu * 16;
    const _Float16* yrow = &ys[(n0 + lm) * YSTR + quad * 8];
    half8 bf0 = *(const half8*)(yrow);
    half8 bf1 = *(const half8*)(yrow + 32);
    half8 bf2 = *(const half8*)(yrow + 64);
    half8 bf3 = *(const half8*)(yrow + 96);
    #pragma unroll
    for (int m0 = 0; m0 < 4; ++m0) {
      f32x4 c = {0.f, 0.f, 0.f, 0.f};
      c = __builtin_amdgcn_mfma_f32_16x16x32_f16(wf[m0][0], bf0, c, 0, 0, 0);
      c = __builtin_amdgcn_mfma_f32_16x16x32_f16(wf[m0][1], bf1, c, 0, 0, 0);
      c = __builtin_amdgcn_mfma_f32_16x16x32_f16(wf[m0][2], bf2, c, 0, 0, 0);
      c = __builtin_amdgcn_mfma_f32_16x16x32_f16(wf[m0][3], bf3, c, 0, 0, 0);
      #pragma unroll
      for (int r = 0; r < 4; ++r) {
        float vv = fast_tanh(c[r]);
        float p = __shfl_xor(vv, 1);   // partner col = other input, same t
        loss += fabsf(vv - p);
      }
    }
  }

  // block reduction -> one double atomic per wg, spread over 128 slots
  #pragma unroll
  for (int off = 32; off > 0; off >>= 1) loss += __shfl_down(loss, off);
  if ((tid & 63) == 0) red[tid >> 6] = loss;
  __syncthreads();
  if (tid == 0) {
    int slot = (blockIdx.x * 4 + blockIdx.y) & (NSLOT - 1);
    atomicAdd(&wsum[slot], (double)(red[0] + red[1] + red[2] + red[3]));
  }
}

__global__ __launch_bounds__(128) void finalize(
    const double* __restrict__ wsum, float* __restrict__ out) {
  __shared__ double part[2];
  int tid = threadIdx.x;
  double v = wsum[tid];
  #pragma unroll
  for (int off = 32; off > 0; off >>= 1) v += __shfl_down(v, off);
  if ((tid & 63) == 0) part[tid >> 6] = v;
  __syncthreads();
  if (tid == 0) out[0] = (float)((part[0] + part[1]) / DENOM);
}

extern "C" void kernel_launch(void* const* d_in, const int* in_sizes, int n_in,
                              void* d_out, int out_size, void* d_ws, size_t ws_size,
                              hipStream_t stream) {
  const float* pred = (const float*)d_in[0];
  const float* tgt  = (const float*)d_in[1];
  const void* a1p = d_in[2];
  const void* a2p = d_in[3];
  const void* b0p = d_in[4];
  const float* W  = (const float*)d_in[5];
  float* out = (float*)d_out;

  double* base = (double*)d_ws;
  double* wsum = base;                                   // [128]
  double* fbuf = base + NSLOT;                           // [750][1024][2] f64
  double* sbuf = fbuf + (size_t)PBLK * 1024 * 2;         // [30][1024][2]
  double* tbuf = sbuf + (size_t)NSEG * 1024 * 2;         // [30][1024][2]
  float2* jbuf = (float2*)(tbuf + (size_t)NSEG * 1024 * 2);  // [626][1024] f32x2

  hipMemsetAsync(wsum, 0, NSLOT * sizeof(double), stream);
  pass1<<<dim3(PBLK, 16), 64, 0, stream>>>(pred, tgt, a1p, a2p, b0p, fbuf);
  pass2a<<<NSEG * 16, 64, 0, stream>>>(a1p, a2p, fbuf, sbuf);
  pass2b<<<dim3(4), 256, 0, stream>>>(a1p, a2p, sbuf, tbuf);
  pass2c<<<dim3(251, 16), 64, 0, stream>>>(pred, tgt, a1p, a2p, b0p,
                                           fbuf, tbuf, jbuf);
  pass3<<<dim3(NJV, BATCH), 256, 0, stream>>>(pred, tgt, a1p, a2p, b0p,
                                              W, jbuf, wsum);
  finalize<<<1, 128, 0, stream>>>(wsum, out);
}